// Round 3
// baseline (150.304 us; speedup 1.0000x reference)
//
#include <hip/hip_runtime.h>
#include <hip/hip_bf16.h>

#define NBH     32          // B*H
#define SEQ     2048
#define DIM     64
#define QBLK    64
#define KBLK    64
#define NCHUNK  (SEQ / KBLK)     // 32

typedef __attribute__((ext_vector_type(4))) float f32x4;
typedef __attribute__((ext_vector_type(8))) short bf16x8;

__device__ __forceinline__ unsigned short bfbits(float f) {
    return __builtin_bit_cast(unsigned short, __float2bfloat16(f));
}

// ---------------------------------------------------------------------------
// V prep: convert V (fp32) into MFMA-B-fragment-ordered bf16 in ws.
// ws[bh][t][ks][dt][lane][j], 16B per (lane): element j is
//   V[bh][t*64 + ks*32 + (lane>>4)*8 + j][dt*16 + (lane&15)]
// ---------------------------------------------------------------------------
__global__ __launch_bounds__(256)
void vprep_kernel(const float* __restrict__ v, unsigned short* __restrict__ wsv)
{
    const int blk = blockIdx.x;            // bh*32 + t
    const int bh  = blk >> 5, t = blk & 31;
    const float* vp = v + ((size_t)bh * SEQ + t * KBLK) * DIM;
    unsigned short* op = wsv + (size_t)blk * 4096;

    for (int fl = threadIdx.x; fl < 512; fl += 256) {
        const int ks = fl >> 8, dt = (fl >> 6) & 3, lane = fl & 63;
        const int g = lane >> 4, c = lane & 15;
        const float* sp = vp + (ks * 32 + g * 8) * DIM + dt * 16 + c;
        bf16x8 frag;
#pragma unroll
        for (int j = 0; j < 8; ++j)
            frag[j] = (short)bfbits(sp[j * DIM]);
        *reinterpret_cast<bf16x8*>(op + fl * 8) = frag;
    }
}

// ---------------------------------------------------------------------------
// Main kernel: barrier-free, LDS-free. Each wave owns 16 q-rows; S is loaded
// directly in MFMA-A-fragment layout (lane(g,c): row c, k = g*8..g*8+7).
// ---------------------------------------------------------------------------
__global__ __launch_bounds__(256, 4)
void softmaxv_kernel(const float* __restrict__ scores,
                     const unsigned short* __restrict__ vfrags,
                     float* __restrict__ out)
{
    const int tid  = threadIdx.x;
    const int w    = tid >> 6;
    const int lane = tid & 63;
    const int g    = lane >> 4;       // 0..3
    const int c    = lane & 15;       // 0..15

    const int bid = blockIdx.x;
    const int bh  = bid >> 5;         // 0..31
    const int qb  = bid & 31;
    const int q0  = qb * QBLK;

    // this thread's S row (= its A-fragment row) and k-base g*8
    const float* sp = scores + ((size_t)bh * SEQ + q0 + w * 16 + c) * SEQ + g * 8;
    const unsigned short* vb = vfrags + (size_t)bh * NCHUNK * 4096 + lane * 8;

    f32x4 acc[4];
#pragma unroll
    for (int dt = 0; dt < 4; ++dt) acc[dt] = (f32x4)0.0f;
    float lsum[4] = {0.f, 0.f, 0.f, 0.f};

    // K=64 chunk: floats at sp + t*64 + {0,4,32,36}  (ks=0: +0,+4; ks=1: +32,+36)
#define SLOADS(dst, t)                                                         \
    {                                                                          \
        dst[0] = *reinterpret_cast<const f32x4*>(sp + (t) * 64 + 0);           \
        dst[1] = *reinterpret_cast<const f32x4*>(sp + (t) * 64 + 4);           \
        dst[2] = *reinterpret_cast<const f32x4*>(sp + (t) * 64 + 32);          \
        dst[3] = *reinterpret_cast<const f32x4*>(sp + (t) * 64 + 36);          \
    }

#define VLOAD(vf, t)                                                           \
    {                                                                          \
        const unsigned short* vp = vb + (t) * 4096;                            \
        _Pragma("unroll")                                                      \
        for (int ks = 0; ks < 2; ++ks)                                         \
            _Pragma("unroll")                                                  \
            for (int dt = 0; dt < 4; ++dt)                                     \
                vf[ks][dt] = *reinterpret_cast<const bf16x8*>(                 \
                    vp + (ks * 4 + dt) * 512);                                 \
    }

    auto compute = [&](const f32x4 (&sreg)[4], const bf16x8 (&vf)[2][4]) {
        bf16x8 pfrag[2];
#pragma unroll
        for (int ks = 0; ks < 2; ++ks) {
            const f32x4 a = sreg[ks * 2], b = sreg[ks * 2 + 1];
            float e0 = __expf(a[0]), e1 = __expf(a[1]);
            float e2 = __expf(a[2]), e3 = __expf(a[3]);
            float e4 = __expf(b[0]), e5 = __expf(b[1]);
            float e6 = __expf(b[2]), e7 = __expf(b[3]);
            lsum[ks * 2]     += (e0 + e1) + (e2 + e3);
            lsum[ks * 2 + 1] += (e4 + e5) + (e6 + e7);
            bf16x8 p;
            p[0] = (short)bfbits(e0); p[1] = (short)bfbits(e1);
            p[2] = (short)bfbits(e2); p[3] = (short)bfbits(e3);
            p[4] = (short)bfbits(e4); p[5] = (short)bfbits(e5);
            p[6] = (short)bfbits(e6); p[7] = (short)bfbits(e7);
            pfrag[ks] = p;
        }
#pragma unroll
        for (int ks = 0; ks < 2; ++ks)
#pragma unroll
            for (int dt = 0; dt < 4; ++dt)
                acc[dt] = __builtin_amdgcn_mfma_f32_16x16x32_bf16(
                    pfrag[ks], vf[ks][dt], acc[dt], 0, 0, 0);
    };

    f32x4 sA[4], sB[4];
    SLOADS(sA, 0)
    for (int t = 0; t < NCHUNK; t += 2) {
        bf16x8 vfA[2][4];
        VLOAD(vfA, t)                       // V first: MFMA's counted vmcnt
        SLOADS(sB, t + 1)                   // leaves this prefetch in flight
        compute(sA, vfA);
        bf16x8 vfB[2][4];
        VLOAD(vfB, t + 1)
        if (t + 2 < NCHUNK) SLOADS(sA, t + 2)
        compute(sB, vfB);
    }
#undef SLOADS
#undef VLOAD

    // ---- epilogue: row-sum reduce (k is split across g and the xor-16/32 pairs)
    float l = (lsum[0] + lsum[1]) + (lsum[2] + lsum[3]);
    l += __shfl_xor(l, 16);
    l += __shfl_xor(l, 32);
    // every lane now holds rowsum for its row c; fetch rowsum for rows g*4+r
    float rinv[4];
#pragma unroll
    for (int r = 0; r < 4; ++r)
        rinv[r] = 1.0f / __shfl(l, g * 4 + r);

    float* op = out + ((size_t)bh * SEQ + q0 + w * 16) * DIM;
#pragma unroll
    for (int dt = 0; dt < 4; ++dt)
#pragma unroll
        for (int r = 0; r < 4; ++r)
            op[(g * 4 + r) * DIM + dt * 16 + c] = acc[dt][r] * rinv[r];
}

extern "C" void kernel_launch(void* const* d_in, const int* in_sizes, int n_in,
                              void* d_out, int out_size, void* d_ws, size_t ws_size,
                              hipStream_t stream)
{
    const float* scores = (const float*)d_in[0];
    const float* v      = (const float*)d_in[1];
    float* out          = (float*)d_out;
    unsigned short* wsv = (unsigned short*)d_ws;   // 8 MB of ws used

    vprep_kernel<<<dim3(NBH * NCHUNK), dim3(256), 0, stream>>>(v, wsv);
    softmaxv_kernel<<<dim3(NBH * (SEQ / QBLK)), dim3(256), 0, stream>>>(scores, wsv, out);
}